// Round 10
// baseline (260.323 us; speedup 1.0000x reference)
//
#include <hip/hip_runtime.h>
#include <hip/hip_fp16.h>

#define NN 100000
#define NE 3200000
#define H  64

#define BSHIFT 7
#define BNODES 128
#define NB ((NN + BNODES - 1) / BNODES)          // 782 buckets

#define PTHREADS 1024
#define PCHUNK   8192
#define PEPT     (PCHUNK / PTHREADS)             // 8
#define NPBLK    ((NE + PCHUNK - 1) / PCHUNK)    // 391

#define ECAP 5120                                // per-bucket slot (padded total <= ~4600)

#define NENC ((NN + 63) / 64)                    // 1563 encoder blocks (64 nodes each)
#define NPRE 65                                  // prepack blocks
#define NFUSED (NPBLK + NENC + NPRE)             // 2019

// ------- dispatch 1 (fused): partition | encoder | prepack ---------------------------
// R23 partition v2: the scan + stage[]/gpos[] reorder existed only to coalesce the
// staging write. staging (16 MB) is L2-resident and each block writes ~10.5 edges
// per bucket in a burst (~3.2 MB live lines per XCD < 4 MB L2) -> direct scattered
// write is absorbed. Per edge: 2 LDS atomics + 1 store. LDS 75 KB -> 32 KB.
__global__ __launch_bounds__(1024, 8) void fused_pre_kernel(
    const int* __restrict__ src, const int* __restrict__ dst,
    int* __restrict__ bfill, unsigned* __restrict__ staging,
    const float* __restrict__ x,
    const float* __restrict__ W1, const float* __restrict__ b1,
    const float* __restrict__ W2, const float* __restrict__ b2,
    __half* __restrict__ h16,
    const float* __restrict__ Wf1, const float* __restrict__ Wf2,
    const float* __restrict__ Ws1, const float* __restrict__ bs1,
    const float* __restrict__ Ws2, const float* __restrict__ bs2,
    const float* __restrict__ Wt1, const float* __restrict__ bt1,
    const float* __restrict__ Wt2, const float* __restrict__ bt2,
    float* __restrict__ wf1t, float* __restrict__ wf2t,
    float* __restrict__ wht,  float* __restrict__ bhead,
    float* __restrict__ wfin, float* __restrict__ bfin)
{
    __shared__ __align__(16) char smem[32768];
    const int t   = threadIdx.x;
    const int blk = blockIdx.x;

    if (blk < NPBLK) {
        // ---------------- partition branch v2 (hist -> reserve -> direct scatter) ----
        int* lh   = (int*)smem;                    // NB counts
        int* lcur = (int*)(smem + 3136);           // NB running global positions

        const int cbase = blk * PCHUNK;
        const int cnt = min(PCHUNK, NE - cbase);

        for (int i = t; i < NB; i += PTHREADS) lh[i] = 0;
        __syncthreads();

        unsigned ent[PEPT];
        int bkt[PEPT];
        const int tbase = t * PEPT;
        if (tbase + PEPT <= cnt) {       // vector path (all blocks except last's tail)
            const int4 s0 = *reinterpret_cast<const int4*>(&src[cbase + tbase]);
            const int4 s1 = *reinterpret_cast<const int4*>(&src[cbase + tbase + 4]);
            const int4 d0 = *reinterpret_cast<const int4*>(&dst[cbase + tbase]);
            const int4 d1 = *reinterpret_cast<const int4*>(&dst[cbase + tbase + 4]);
            const int sa_[8] = {s0.x, s0.y, s0.z, s0.w, s1.x, s1.y, s1.z, s1.w};
            const int da_[8] = {d0.x, d0.y, d0.z, d0.w, d1.x, d1.y, d1.z, d1.w};
            #pragma unroll
            for (int j = 0; j < PEPT; ++j) {
                bkt[j] = sa_[j] >> BSHIFT;
                ent[j] = (unsigned)da_[j] | ((unsigned)(sa_[j] & (BNODES - 1)) << 17);
                atomicAdd(&lh[bkt[j]], 1);
            }
        } else {
            #pragma unroll
            for (int j = 0; j < PEPT; ++j) {
                const int idx = tbase + j;
                if (idx < cnt) {
                    const int s_ = src[cbase + idx];
                    const int d_ = dst[cbase + idx];
                    bkt[j] = s_ >> BSHIFT;
                    ent[j] = (unsigned)d_ | ((unsigned)(s_ & (BNODES - 1)) << 17);
                    atomicAdd(&lh[bkt[j]], 1);
                } else bkt[j] = -1;
            }
        }
        __syncthreads();

        // reserve this block's segment of each touched bucket; lcur = global cursor
        if (t < NB) {
            const int hv = lh[t];
            if (hv > 0) lcur[t] = t * ECAP + atomicAdd(&bfill[t], hv);
        }
        __syncthreads();

        // direct scattered write (L2-absorbed; see header comment)
        #pragma unroll
        for (int j = 0; j < PEPT; ++j) {
            if (bkt[j] >= 0) {
                const int pos = atomicAdd(&lcur[bkt[j]], 1);
                staging[pos] = ent[j];
            }
        }

    } else if (blk < NPBLK + NENC) {
        // ---------------- encoder branch (R17 math; self-staged W2) ----------------
        float* sh  = (float*)smem;                 // [64][64] = 16 KB
        float* w2s = (float*)(smem + 16384);       // transposed W2, 16 KB

        {
            const int i4 = t * 4;                  // 1024 threads x float4 = 4096
            const float4 wv4 = *reinterpret_cast<const float4*>(&W2[i4]);
            const int k = i4 >> 6, f0 = i4 & 63;
            const int dbase = (k >> 2) * 256 + (k & 3);
            w2s[dbase + (f0 + 0) * 4] = wv4.x;
            w2s[dbase + (f0 + 1) * 4] = wv4.y;
            w2s[dbase + (f0 + 2) * 4] = wv4.z;
            w2s[dbase + (f0 + 3) * 4] = wv4.w;
        }
        __syncthreads();

        const int w  = t >> 6;                     // wave 0..15
        const int f  = t & 63;
        const int nw = (blk - NPBLK) * 64 + w * 4; // 4 nodes per wave
        if (nw < NN) {
            const float xv = (f < 24) ? x[nw * 6 + f] : 0.0f;

            const float bb1 = b1[f];
            float w1r[6];
            #pragma unroll
            for (int k = 0; k < 6; ++k) w1r[k] = W1[k * H + f];

            #pragma unroll
            for (int j = 0; j < 4; ++j) {
                float acc = bb1;
                #pragma unroll
                for (int k = 0; k < 6; ++k)
                    acc = fmaf(__shfl(xv, j * 6 + k), w1r[k], acc);
                sh[(w * 4 + j) * H + f] = fmaxf(acc, 0.0f);   // same-wave, no barrier
            }
            const float bb2 = b2[f];
            float o0 = bb2, o1 = bb2, o2 = bb2, o3 = bb2;
            #pragma unroll
            for (int k4 = 0; k4 < 16; ++k4) {
                const float4 wv = *reinterpret_cast<const float4*>(&w2s[(k4 * 64 + f) * 4]);
                const float4 a0 = *reinterpret_cast<const float4*>(&sh[(w * 4 + 0) * H + k4 * 4]);
                const float4 a1 = *reinterpret_cast<const float4*>(&sh[(w * 4 + 1) * H + k4 * 4]);
                const float4 a2 = *reinterpret_cast<const float4*>(&sh[(w * 4 + 2) * H + k4 * 4]);
                const float4 a3 = *reinterpret_cast<const float4*>(&sh[(w * 4 + 3) * H + k4 * 4]);
                o0 = fmaf(a0.x, wv.x, o0); o0 = fmaf(a0.y, wv.y, o0); o0 = fmaf(a0.z, wv.z, o0); o0 = fmaf(a0.w, wv.w, o0);
                o1 = fmaf(a1.x, wv.x, o1); o1 = fmaf(a1.y, wv.y, o1); o1 = fmaf(a1.z, wv.z, o1); o1 = fmaf(a1.w, wv.w, o1);
                o2 = fmaf(a2.x, wv.x, o2); o2 = fmaf(a2.y, wv.y, o2); o2 = fmaf(a2.z, wv.z, o2); o2 = fmaf(a2.w, wv.w, o2);
                o3 = fmaf(a3.x, wv.x, o3); o3 = fmaf(a3.y, wv.y, o3); o3 = fmaf(a3.z, wv.z, o3); o3 = fmaf(a3.w, wv.w, o3);
            }
            h16[((size_t)(nw + 0) << 6) + f] = __float2half(o0);
            h16[((size_t)(nw + 1) << 6) + f] = __float2half(o1);
            h16[((size_t)(nw + 2) << 6) + f] = __float2half(o2);
            h16[((size_t)(nw + 3) << 6) + f] = __float2half(o3);
        }

    } else {
        // ---------------- prepack branch (gather weight tables) ----------------
        const int pb = blk - NPBLK - NENC;         // 0..64
        if (pb < 64) {
            if (t < 256) {
                const int e   = pb * 256 + t;      // 0..16383
                const int a   = e >> 12;
                const int idx = e & 4095;
                const int k4  = idx >> 8;
                const int ff  = (idx >> 2) & 63;
                const int j   = idx & 3;
                if (a == 0)      wf1t[idx] = Wf1[k4 * 256 + j * 64 + ff];
                else if (a == 1) wf2t[idx] = Wf2[k4 * 256 + j * 64 + ff];
                else if (a == 2) wht[idx]  = (ff < 32) ? Ws1[k4 * 128 + j * 32 + ff]
                                                       : Wt1[k4 * 128 + j * 32 + (ff - 32)];
            }
        } else {
            if (t < 64) bhead[t] = (t < 32) ? bs1[t] : bt1[t - 32];
            if (t < 160) {
                const int c = t >> 5, jj = t & 31;
                wfin[t] = (c == 0) ? Ws2[jj] : Wt2[jj * 4 + (c - 1)];
            }
            if (t < 5) bfin[t] = (t == 0) ? bs2[0] : bt2[t - 1];
        }
    }
}

// ------- dispatch 2: bucket sort (R22-verified direct scatter) -----------------------
__global__ __launch_bounds__(1024) void bucket_sort_kernel(
    const unsigned* __restrict__ staging, const int* __restrict__ bfill,
    int* __restrict__ sdst, int* __restrict__ offs, int* __restrict__ counts)
{
    __shared__ int cntS[BNODES];
    __shared__ int scanS[BNODES];
    __shared__ int lstart[BNODES];
    __shared__ int lcur[BNODES];
    const int t = threadIdx.x;
    const int b = blockIdx.x;
    const int base0 = b * ECAP;
    const int ecnt  = bfill[b];

    if (t < BNODES) cntS[t] = 0;
    __syncthreads();

    const uint4 e0 = *reinterpret_cast<const uint4*>(&staging[base0 + t * 4]);
    uint4 e1 = make_uint4(0u, 0u, 0u, 0u);
    if (ecnt > 4096)                     // block-uniform branch
        e1 = *reinterpret_cast<const uint4*>(&staging[base0 + 4096 + t * 4]);
    const unsigned ev[8] = {e0.x, e0.y, e0.z, e0.w, e1.x, e1.y, e1.z, e1.w};
    int iv[8];
    #pragma unroll
    for (int u = 0; u < 8; ++u)
        iv[u] = (u < 4) ? (t * 4 + u) : (4096 + t * 4 + (u - 4));

    #pragma unroll
    for (int u = 0; u < 8; ++u)
        if (iv[u] < ecnt) atomicAdd(&cntS[ev[u] >> 17], 1);
    __syncthreads();

    if (t < BNODES) scanS[t] = (cntS[t] + 3) & ~3;   // padded counts
    __syncthreads();
    for (int off = 1; off < BNODES; off <<= 1) {
        int xv = 0;
        if (t >= off && t < BNODES) xv = scanS[t - off];
        __syncthreads();
        if (t >= off && t < BNODES) scanS[t] += xv;
        __syncthreads();
    }
    if (t < BNODES) {
        const int st = scanS[t] - ((cntS[t] + 3) & ~3);
        lstart[t] = st;
        lcur[t]   = st;
    }
    __syncthreads();

    #pragma unroll
    for (int u = 0; u < 8; ++u)
        if (iv[u] < ecnt) {
            const int lp = atomicAdd(&lcur[(int)(ev[u] >> 17)], 1);
            sdst[base0 + lp] = (int)(ev[u] & 0x1FFFFu);   // direct L2-resident scatter
        }

    const int nbase = b * BNODES;
    if (t < BNODES && nbase + t < NN) {
        offs[nbase + t]   = base0 + lstart[t];
        counts[nbase + t] = cntS[t];
    }
}

// ------- dispatch 3: fused gather(mean)+MLP+heads — R16/R21-verified 104.7us form ----
// Byte-exact revert: R19 (3-bank, compiler-serialized) and R22 (static schedule,
// spilled at VGPR 64 / WRITE_SIZE 8.6k) both lost to this 2-bank structure. Floored.
#define ACC4(cv, u)                                                            \
    {                                                                          \
        const float m = (rem > (u)) ? 1.0f : 0.0f;                             \
        const __half2* ph = reinterpret_cast<const __half2*>(&(cv));           \
        const float2 p0 = __half22float2(ph[0]);                               \
        const float2 p1 = __half22float2(ph[1]);                               \
        const float2 p2 = __half22float2(ph[2]);                               \
        const float2 p3 = __half22float2(ph[3]);                               \
        acc0 = fmaf(m, p0.x, acc0); acc1 = fmaf(m, p0.y, acc1);                \
        acc2 = fmaf(m, p1.x, acc2); acc3 = fmaf(m, p1.y, acc3);                \
        acc4 = fmaf(m, p2.x, acc4); acc5 = fmaf(m, p2.y, acc5);                \
        acc6 = fmaf(m, p3.x, acc6); acc7 = fmaf(m, p3.y, acc7);                \
    }

#define FLUSHN(jj)                                                             \
    {                                                                          \
        float4* w0 = reinterpret_cast<float4*>(&sp[r][g << 3]);                \
        w0[0] = make_float4(acc0, acc1, acc2, acc3);                           \
        w0[1] = make_float4(acc4, acc5, acc6, acc7);                           \
        const float ssum = sp[0][f] + sp[1][f] + sp[2][f] + sp[3][f]           \
                         + sp[4][f] + sp[5][f] + sp[6][f] + sp[7][f];          \
        const int dgj = DGf(jj);                                               \
        sa[jj][f] = SVf(jj) + ssum * (1.0f / fmaxf((float)dgj, 1.0f));         \
        acc0 = acc1 = acc2 = acc3 = acc4 = acc5 = acc6 = acc7 = 0.0f;          \
    }

#define GSTEP(c0, c1, c2, c3, n0_, n1_, n2_, n3_)                              \
    {                                                                          \
        if (jn < 4) { /* fill bank N for chunk (jn,bn) */                      \
            const int rem = DGf(jn) - bn - 4 * r;                              \
            const int i0 = (rem > 0) ? idxN.x : 0;                             \
            const int i1 = (rem > 1) ? idxN.y : 0;                             \
            const int i2 = (rem > 2) ? idxN.z : 0;                             \
            const int i3 = (rem > 3) ? idxN.w : 0;                             \
            n0_ = *reinterpret_cast<const int4*>(hbase + ((size_t)i0 << 6));   \
            n1_ = *reinterpret_cast<const int4*>(hbase + ((size_t)i1 << 6));   \
            n2_ = *reinterpret_cast<const int4*>(hbase + ((size_t)i2 << 6));   \
            n3_ = *reinterpret_cast<const int4*>(hbase + ((size_t)i3 << 6));   \
        }                                                                      \
        int jm = jn, bm = bn; adv(jm, bm);                                     \
        idxN = IDXL(jm, bm);                                                   \
        { /* consume bank C for chunk (jc,bc) */                               \
            const int rem = DGf(jc) - bc - 4 * r;                              \
            ACC4(c0, 0); ACC4(c1, 1); ACC4(c2, 2); ACC4(c3, 3);                \
        }                                                                      \
        if (jn != jc) FLUSHN(jc);                                              \
        jc = jn; bc = bn; jn = jm; bn = bm;                                    \
    }

__global__ __launch_bounds__(64, 4) void gather_head_kernel(
    const __half* __restrict__ h16,
    const int* __restrict__ counts, const int* __restrict__ offs,
    const int* __restrict__ sdst,
    const float* __restrict__ wf1t, const float* __restrict__ bf1,
    const float* __restrict__ wf2t, const float* __restrict__ bf2,
    const float* __restrict__ wht,  const float* __restrict__ bhead,
    const float* __restrict__ wfin, const float* __restrict__ bfin,
    float* __restrict__ out_scores, float* __restrict__ out_types)
{
    __shared__ float sa[4][H];
    __shared__ float sb[4][H];
    __shared__ float sp[8][H];           // 2 KB row-slot partials
    const int f  = threadIdx.x;          // 0..63
    const int n0 = blockIdx.x * 4;       // grid 25000 -> n0+3 < NN always
    const int g  = f & 7;                // feature-group (16B at g*16 within a row)
    const int r  = f >> 3;               // row-slot (4 consecutive edges per slot)
    const __half* __restrict__ hbase = h16 + (g << 3);

    const int dg0 = counts[n0 + 0], dg1 = counts[n0 + 1],
              dg2 = counts[n0 + 2], dg3 = counts[n0 + 3];
    const int st0 = offs[n0 + 0], st1 = offs[n0 + 1],
              st2 = offs[n0 + 2], st3 = offs[n0 + 3];

    const float sv0 = __half2float(h16[((size_t)(n0 + 0) << 6) + f]);
    const float sv1 = __half2float(h16[((size_t)(n0 + 1) << 6) + f]);
    const float sv2 = __half2float(h16[((size_t)(n0 + 2) << 6) + f]);
    const float sv3 = __half2float(h16[((size_t)(n0 + 3) << 6) + f]);
    sa[0][f] = sv0; sa[1][f] = sv1; sa[2][f] = sv2; sa[3][f] = sv3;  // deg-0 default

    auto DGf = [&](int j) { return j == 0 ? dg0 : j == 1 ? dg1 : j == 2 ? dg2 : dg3; };
    auto STf = [&](int j) { return j == 0 ? st0 : j == 1 ? st1 : j == 2 ? st2 : st3; };
    auto SVf = [&](int j) { return j == 0 ? sv0 : j == 1 ? sv1 : j == 2 ? sv2 : sv3; };
    auto adv = [&](int& j, int& b) {
        if (j >= 4) return;
        b += 32;
        if (b >= DGf(j)) { b = 0; do { ++j; } while (j < 4 && DGf(j) == 0); }
    };
    auto IDXL = [&](int j, int b) -> int4 {   // 16B-aligned: starts padded to 4 ints
        if (j < 4) return *reinterpret_cast<const int4*>(&sdst[STf(j) + b + 4 * r]);
        return make_int4(0, 0, 0, 0);
    };

    float acc0 = 0.f, acc1 = 0.f, acc2 = 0.f, acc3 = 0.f,
          acc4 = 0.f, acc5 = 0.f, acc6 = 0.f, acc7 = 0.f;
    int4 A0 = make_int4(0,0,0,0), A1 = A0, A2 = A0, A3 = A0;
    int4 B0 = A0, B1 = A0, B2 = A0, B3 = A0;

    // --- pipeline prologue ---
    int jc = 0, bc = 0;
    while (jc < 4 && DGf(jc) == 0) ++jc;
    int jn = jc, bn = bc; adv(jn, bn);
    int4 idxC = IDXL(jc, bc);
    int4 idxN = IDXL(jn, bn);
    if (jc < 4) {                         // fill bank A for first chunk
        const int rem = DGf(jc) - bc - 4 * r;
        const int i0 = (rem > 0) ? idxC.x : 0;
        const int i1 = (rem > 1) ? idxC.y : 0;
        const int i2 = (rem > 2) ? idxC.z : 0;
        const int i3 = (rem > 3) ? idxC.w : 0;
        A0 = *reinterpret_cast<const int4*>(hbase + ((size_t)i0 << 6));
        A1 = *reinterpret_cast<const int4*>(hbase + ((size_t)i1 << 6));
        A2 = *reinterpret_cast<const int4*>(hbase + ((size_t)i2 << 6));
        A3 = *reinterpret_cast<const int4*>(hbase + ((size_t)i3 << 6));
    }

    while (jc < 4) {
        GSTEP(A0, A1, A2, A3, B0, B1, B2, B3);
        if (jc >= 4) break;
        GSTEP(B0, B1, B2, B3, A0, A1, A2, A3);
    }

    // ---- layer 1: sa -> sb (relu), one weight dwordx4 feeds 4 k x 4 nodes ----
    {
        const float bb = bf1[f];
        float o0 = bb, o1 = bb, o2 = bb, o3 = bb;
        #pragma unroll
        for (int k4 = 0; k4 < 16; ++k4) {
            const float4 w  = *reinterpret_cast<const float4*>(&wf1t[(k4 * 64 + f) * 4]);
            const float4 a0 = *reinterpret_cast<const float4*>(&sa[0][k4 * 4]);
            const float4 a1 = *reinterpret_cast<const float4*>(&sa[1][k4 * 4]);
            const float4 a2 = *reinterpret_cast<const float4*>(&sa[2][k4 * 4]);
            const float4 a3 = *reinterpret_cast<const float4*>(&sa[3][k4 * 4]);
            o0 = fmaf(a0.x, w.x, o0); o0 = fmaf(a0.y, w.y, o0); o0 = fmaf(a0.z, w.z, o0); o0 = fmaf(a0.w, w.w, o0);
            o1 = fmaf(a1.x, w.x, o1); o1 = fmaf(a1.y, w.y, o1); o1 = fmaf(a1.z, w.z, o1); o1 = fmaf(a1.w, w.w, o1);
            o2 = fmaf(a2.x, w.x, o2); o2 = fmaf(a2.y, w.y, o2); o2 = fmaf(a2.z, w.z, o2); o2 = fmaf(a2.w, w.w, o2);
            o3 = fmaf(a3.x, w.x, o3); o3 = fmaf(a3.y, w.y, o3); o3 = fmaf(a3.z, w.z, o3); o3 = fmaf(a3.w, w.w, o3);
        }
        sb[0][f] = fmaxf(o0, 0.0f);
        sb[1][f] = fmaxf(o1, 0.0f);
        sb[2][f] = fmaxf(o2, 0.0f);
        sb[3][f] = fmaxf(o3, 0.0f);
    }

    // ---- layer 2: sb -> sa (relu) ----
    {
        const float bb = bf2[f];
        float o0 = bb, o1 = bb, o2 = bb, o3 = bb;
        #pragma unroll
        for (int k4 = 0; k4 < 16; ++k4) {
            const float4 w  = *reinterpret_cast<const float4*>(&wf2t[(k4 * 64 + f) * 4]);
            const float4 a0 = *reinterpret_cast<const float4*>(&sb[0][k4 * 4]);
            const float4 a1 = *reinterpret_cast<const float4*>(&sb[1][k4 * 4]);
            const float4 a2 = *reinterpret_cast<const float4*>(&sb[2][k4 * 4]);
            const float4 a3 = *reinterpret_cast<const float4*>(&sb[3][k4 * 4]);
            o0 = fmaf(a0.x, w.x, o0); o0 = fmaf(a0.y, w.y, o0); o0 = fmaf(a0.z, w.z, o0); o0 = fmaf(a0.w, w.w, o0);
            o1 = fmaf(a1.x, w.x, o1); o1 = fmaf(a1.y, w.y, o1); o1 = fmaf(a1.z, w.z, o1); o1 = fmaf(a1.w, w.w, o1);
            o2 = fmaf(a2.x, w.x, o2); o2 = fmaf(a2.y, w.y, o2); o2 = fmaf(a2.z, w.z, o2); o2 = fmaf(a2.w, w.w, o2);
            o3 = fmaf(a3.x, w.x, o3); o3 = fmaf(a3.y, w.y, o3); o3 = fmaf(a3.z, w.z, o3); o3 = fmaf(a3.w, w.w, o3);
        }
        sa[0][f] = fmaxf(o0, 0.0f);
        sa[1][f] = fmaxf(o1, 0.0f);
        sa[2][f] = fmaxf(o2, 0.0f);
        sa[3][f] = fmaxf(o3, 0.0f);
    }

    // ---- heads layer (merged Ws1|Wt1): sa -> sb (relu) ----
    {
        const float bb = bhead[f];
        float o0 = bb, o1 = bb, o2 = bb, o3 = bb;
        #pragma unroll
        for (int k4 = 0; k4 < 16; ++k4) {
            const float4 w  = *reinterpret_cast<const float4*>(&wht[(k4 * 64 + f) * 4]);
            const float4 a0 = *reinterpret_cast<const float4*>(&sa[0][k4 * 4]);
            const float4 a1 = *reinterpret_cast<const float4*>(&sa[1][k4 * 4]);
            const float4 a2 = *reinterpret_cast<const float4*>(&sa[2][k4 * 4]);
            const float4 a3 = *reinterpret_cast<const float4*>(&sa[3][k4 * 4]);
            o0 = fmaf(a0.x, w.x, o0); o0 = fmaf(a0.y, w.y, o0); o0 = fmaf(a0.z, w.z, o0); o0 = fmaf(a0.w, w.w, o0);
            o1 = fmaf(a1.x, w.x, o1); o1 = fmaf(a1.y, w.y, o1); o1 = fmaf(a1.z, w.z, o1); o1 = fmaf(a1.w, w.w, o1);
            o2 = fmaf(a2.x, w.x, o2); o2 = fmaf(a2.y, w.y, o2); o2 = fmaf(a2.z, w.z, o2); o2 = fmaf(a2.w, w.w, o2);
            o3 = fmaf(a3.x, w.x, o3); o3 = fmaf(a3.y, w.y, o3); o3 = fmaf(a3.z, w.z, o3); o3 = fmaf(a3.w, w.w, o3);
        }
        sb[0][f] = fmaxf(o0, 0.0f);
        sb[1][f] = fmaxf(o1, 0.0f);
        sb[2][f] = fmaxf(o2, 0.0f);
        sb[3][f] = fmaxf(o3, 0.0f);
    }

    // ---- final: j = f>>4 (node), c = f&15 (output, active c<5); rotated start ----
    {
        const int j = f >> 4;
        const int c = f & 15;
        if (c < 5) {
            float a2 = bfin[c];
            const int off = (c == 0) ? 0 : 32;
            const int rot = ((c << 2) + (j << 3)) & 31;
            #pragma unroll 8
            for (int jj = 0; jj < 32; ++jj) {
                const int q = (jj + rot) & 31;
                a2 = fmaf(sb[j][off + q], wfin[c * 32 + q], a2);
            }
            const int node = n0 + j;
            if (c == 0) out_scores[node] = a2;
            else        out_types[node * 4 + (c - 1)] = a2;
        }
    }
}

#undef GSTEP
#undef FLUSHN
#undef ACC4

extern "C" void kernel_launch(void* const* d_in, const int* in_sizes, int n_in,
                              void* d_out, int out_size, void* d_ws, size_t ws_size,
                              hipStream_t stream)
{
    const float* x   = (const float*)d_in[0];
    const int*   adj = (const int*)  d_in[1];   // [2, E]: src = adj[0:E], dst = adj[E:2E]
    const float* W1  = (const float*)d_in[2];
    const float* b1  = (const float*)d_in[3];
    const float* W2  = (const float*)d_in[4];
    const float* b2  = (const float*)d_in[5];
    const float* Wf1 = (const float*)d_in[6];
    const float* bf1 = (const float*)d_in[7];
    const float* Wf2 = (const float*)d_in[8];
    const float* bf2 = (const float*)d_in[9];
    const float* Ws1 = (const float*)d_in[10];
    const float* bs1 = (const float*)d_in[11];
    const float* Ws2 = (const float*)d_in[12];
    const float* bs2 = (const float*)d_in[13];
    const float* Wt1 = (const float*)d_in[14];
    const float* bt1 = (const float*)d_in[15];
    const float* Wt2 = (const float*)d_in[16];
    const float* bt2 = (const float*)d_in[17];

    float* out_scores = (float*)d_out;          // [N]
    float* out_types  = out_scores + NN;        // [N,4]

    // ws: staging [NB*ECAP u32] | sdst [NB*ECAP] | h16 [NN*H half] | counts [NN]
    //     | offs [NN] | bfill [784] | wf1t[4096] wf2t[4096] wht[4096]
    //     | bhead[64] wfin[160] bfin[5]
    unsigned* staging = (unsigned*)d_ws;
    int*      sdst    = (int*)(staging + (size_t)NB * ECAP);
    __half*   h16     = (__half*)(sdst + (size_t)NB * ECAP);
    int*      counts  = (int*)(h16 + (size_t)NN * H);
    int*      offs    = counts + NN;
    int*      bfill   = offs + NN;
    float*    wf1t    = (float*)(bfill + 784);   // 16B-aligned (checked)
    float*    wf2t    = wf1t + 4096;
    float*    wht     = wf2t + 4096;
    float*    bhead   = wht + 4096;
    float*    wfin    = bhead + 64;
    float*    bfin    = wfin + 160;

    const int* src = adj;
    const int* dst = adj + NE;

    hipMemsetAsync(bfill, 0, NB * sizeof(int), stream);   // ws is poisoned
    fused_pre_kernel<<<NFUSED, PTHREADS, 0, stream>>>(
        src, dst, bfill, staging,
        x, W1, b1, W2, b2, h16,
        Wf1, Wf2, Ws1, bs1, Ws2, bs2, Wt1, bt1, Wt2, bt2,
        wf1t, wf2t, wht, bhead, wfin, bfin);
    bucket_sort_kernel<<<NB, 1024, 0, stream>>>(staging, bfill, sdst, offs, counts);
    gather_head_kernel<<<NN / 4, 64, 0, stream>>>(h16, counts, offs, sdst,
                                                  wf1t, bf1, wf2t, bf2,
                                                  wht, bhead, wfin, bfin,
                                                  out_scores, out_types);
}

// Round 11
// 241.298 us; speedup vs baseline: 1.0788x; 1.0788x over previous
//
#include <hip/hip_runtime.h>
#include <hip/hip_fp16.h>

#define NN 100000
#define NE 3200000
#define H  64

#define BSHIFT 7
#define BNODES 128
#define NB ((NN + BNODES - 1) / BNODES)          // 782 buckets

#define PTHREADS 1024
#define PCHUNK   8192
#define PEPT     (PCHUNK / PTHREADS)             // 8
#define NPBLK    ((NE + PCHUNK - 1) / PCHUNK)    // 391

#define ECAP 5120                                // per-bucket slot (padded total <= ~4600)

#define NENC ((NN + 63) / 64)                    // 1563 encoder blocks (64 nodes each)
#define NPRE 65                                  // prepack blocks
#define NFUSED (NPBLK + NENC + NPRE)             // 2019

// ------- dispatch 1 (fused): partition | encoder | prepack (R21-verified, 243.8us) ---
// R24: byte-exact revert to the Round-8-verified configuration. The scan +
// stage[]/gpos[] coalescing machinery is load-bearing: direct-scatter variants lost
// twice (R20: 15x write amplification at 32MB; R23: +17us at 16MB).
__global__ __launch_bounds__(1024, 8) void fused_pre_kernel(
    const int* __restrict__ src, const int* __restrict__ dst,
    int* __restrict__ bfill, unsigned* __restrict__ staging,
    const float* __restrict__ x,
    const float* __restrict__ W1, const float* __restrict__ b1,
    const float* __restrict__ W2, const float* __restrict__ b2,
    __half* __restrict__ h16,
    const float* __restrict__ Wf1, const float* __restrict__ Wf2,
    const float* __restrict__ Ws1, const float* __restrict__ bs1,
    const float* __restrict__ Ws2, const float* __restrict__ bs2,
    const float* __restrict__ Wt1, const float* __restrict__ bt1,
    const float* __restrict__ Wt2, const float* __restrict__ bt2,
    float* __restrict__ wf1t, float* __restrict__ wf2t,
    float* __restrict__ wht,  float* __restrict__ bhead,
    float* __restrict__ wfin, float* __restrict__ bfin)
{
    __shared__ __align__(16) char smem[75008];
    const int t   = threadIdx.x;
    const int blk = blockIdx.x;

    if (blk < NPBLK) {
        // ---------------- partition branch (R17/R19 verified) ----------------
        unsigned* stage = (unsigned*)smem;                 // 32 KB
        int*      gpos  = (int*)(smem + 32768);            // 32 KB
        int*      lh    = (int*)(smem + 65536);            // 3128 B
        int*      lcur  = (int*)(smem + 65536 + 3136);     // 3128 B
        int*      gbase = (int*)(smem + 65536 + 6272);     // 3128 B
        int*      wtot  = (int*)(smem + 65536 + 9408);     // 64 B

        const int lane = t & 63;
        const int wid  = t >> 6;
        const int cbase = blk * PCHUNK;
        const int cnt = min(PCHUNK, NE - cbase);

        for (int i = t; i < NB; i += PTHREADS) lh[i] = 0;
        __syncthreads();

        unsigned ent[PEPT];
        int bkt[PEPT];
        const int tbase = t * PEPT;
        if (tbase + PEPT <= cnt) {       // vector path
            const int4 s0 = *reinterpret_cast<const int4*>(&src[cbase + tbase]);
            const int4 s1 = *reinterpret_cast<const int4*>(&src[cbase + tbase + 4]);
            const int4 d0 = *reinterpret_cast<const int4*>(&dst[cbase + tbase]);
            const int4 d1 = *reinterpret_cast<const int4*>(&dst[cbase + tbase + 4]);
            const int sa_[8] = {s0.x, s0.y, s0.z, s0.w, s1.x, s1.y, s1.z, s1.w};
            const int da_[8] = {d0.x, d0.y, d0.z, d0.w, d1.x, d1.y, d1.z, d1.w};
            #pragma unroll
            for (int j = 0; j < PEPT; ++j) {
                bkt[j] = sa_[j] >> BSHIFT;
                ent[j] = (unsigned)da_[j] | ((unsigned)(sa_[j] & (BNODES - 1)) << 17);
                atomicAdd(&lh[bkt[j]], 1);
            }
        } else {
            #pragma unroll
            for (int j = 0; j < PEPT; ++j) {
                const int idx = tbase + j;
                if (idx < cnt) {
                    const int s_ = src[cbase + idx];
                    const int d_ = dst[cbase + idx];
                    bkt[j] = s_ >> BSHIFT;
                    ent[j] = (unsigned)d_ | ((unsigned)(s_ & (BNODES - 1)) << 17);
                    atomicAdd(&lh[bkt[j]], 1);
                } else bkt[j] = -1;
            }
        }
        __syncthreads();

        // wave-shfl exclusive scan over lh (verified R9)
        const int hv = (t < NB) ? lh[t] : 0;
        int incl = hv;
        #pragma unroll
        for (int off = 1; off < 64; off <<= 1) {
            const int n = __shfl_up(incl, off);
            if (lane >= off) incl += n;
        }
        if (lane == 63) wtot[wid] = incl;
        __syncthreads();
        if (wid == 0 && lane < 16) {
            const int v = wtot[lane];
            int s2 = v;
            #pragma unroll
            for (int off = 1; off < 16; off <<= 1) {
                const int n = __shfl_up(s2, off);
                if (lane >= off) s2 += n;
            }
            wtot[lane] = s2 - v;    // exclusive wave offsets
        }
        __syncthreads();
        if (t < NB) {
            const int excl = incl - hv + wtot[wid];
            lh[t]   = excl;
            lcur[t] = excl;
            gbase[t] = t * ECAP + ((hv > 0) ? atomicAdd(&bfill[t], hv) : 0);
        }
        __syncthreads();

        #pragma unroll
        for (int j = 0; j < PEPT; ++j) {
            if (bkt[j] >= 0) {
                const int lp = atomicAdd(&lcur[bkt[j]], 1);
                stage[lp] = ent[j];
                gpos[lp]  = gbase[bkt[j]] + (lp - lh[bkt[j]]);
            }
        }
        __syncthreads();

        for (int i = t; i < cnt; i += PTHREADS)
            staging[gpos[i]] = stage[i];

    } else if (blk < NPBLK + NENC) {
        // ---------------- encoder branch (R17 math; self-staged W2) ----------------
        float* sh  = (float*)smem;                 // [64][64] = 16 KB
        float* w2s = (float*)(smem + 16384);       // transposed W2, 16 KB

        {
            const int i4 = t * 4;                  // 1024 threads x float4 = 4096
            const float4 wv4 = *reinterpret_cast<const float4*>(&W2[i4]);
            const int k = i4 >> 6, f0 = i4 & 63;
            const int dbase = (k >> 2) * 256 + (k & 3);
            w2s[dbase + (f0 + 0) * 4] = wv4.x;
            w2s[dbase + (f0 + 1) * 4] = wv4.y;
            w2s[dbase + (f0 + 2) * 4] = wv4.z;
            w2s[dbase + (f0 + 3) * 4] = wv4.w;
        }
        __syncthreads();

        const int w  = t >> 6;                     // wave 0..15
        const int f  = t & 63;
        const int nw = (blk - NPBLK) * 64 + w * 4; // 4 nodes per wave
        if (nw < NN) {
            const float xv = (f < 24) ? x[nw * 6 + f] : 0.0f;

            const float bb1 = b1[f];
            float w1r[6];
            #pragma unroll
            for (int k = 0; k < 6; ++k) w1r[k] = W1[k * H + f];

            #pragma unroll
            for (int j = 0; j < 4; ++j) {
                float acc = bb1;
                #pragma unroll
                for (int k = 0; k < 6; ++k)
                    acc = fmaf(__shfl(xv, j * 6 + k), w1r[k], acc);
                sh[(w * 4 + j) * H + f] = fmaxf(acc, 0.0f);   // same-wave, no barrier
            }
            const float bb2 = b2[f];
            float o0 = bb2, o1 = bb2, o2 = bb2, o3 = bb2;
            #pragma unroll
            for (int k4 = 0; k4 < 16; ++k4) {
                const float4 wv = *reinterpret_cast<const float4*>(&w2s[(k4 * 64 + f) * 4]);
                const float4 a0 = *reinterpret_cast<const float4*>(&sh[(w * 4 + 0) * H + k4 * 4]);
                const float4 a1 = *reinterpret_cast<const float4*>(&sh[(w * 4 + 1) * H + k4 * 4]);
                const float4 a2 = *reinterpret_cast<const float4*>(&sh[(w * 4 + 2) * H + k4 * 4]);
                const float4 a3 = *reinterpret_cast<const float4*>(&sh[(w * 4 + 3) * H + k4 * 4]);
                o0 = fmaf(a0.x, wv.x, o0); o0 = fmaf(a0.y, wv.y, o0); o0 = fmaf(a0.z, wv.z, o0); o0 = fmaf(a0.w, wv.w, o0);
                o1 = fmaf(a1.x, wv.x, o1); o1 = fmaf(a1.y, wv.y, o1); o1 = fmaf(a1.z, wv.z, o1); o1 = fmaf(a1.w, wv.w, o1);
                o2 = fmaf(a2.x, wv.x, o2); o2 = fmaf(a2.y, wv.y, o2); o2 = fmaf(a2.z, wv.z, o2); o2 = fmaf(a2.w, wv.w, o2);
                o3 = fmaf(a3.x, wv.x, o3); o3 = fmaf(a3.y, wv.y, o3); o3 = fmaf(a3.z, wv.z, o3); o3 = fmaf(a3.w, wv.w, o3);
            }
            h16[((size_t)(nw + 0) << 6) + f] = __float2half(o0);
            h16[((size_t)(nw + 1) << 6) + f] = __float2half(o1);
            h16[((size_t)(nw + 2) << 6) + f] = __float2half(o2);
            h16[((size_t)(nw + 3) << 6) + f] = __float2half(o3);
        }

    } else {
        // ---------------- prepack branch (gather weight tables) ----------------
        const int pb = blk - NPBLK - NENC;         // 0..64
        if (pb < 64) {
            if (t < 256) {
                const int e   = pb * 256 + t;      // 0..16383
                const int a   = e >> 12;
                const int idx = e & 4095;
                const int k4  = idx >> 8;
                const int ff  = (idx >> 2) & 63;
                const int j   = idx & 3;
                if (a == 0)      wf1t[idx] = Wf1[k4 * 256 + j * 64 + ff];
                else if (a == 1) wf2t[idx] = Wf2[k4 * 256 + j * 64 + ff];
                else if (a == 2) wht[idx]  = (ff < 32) ? Ws1[k4 * 128 + j * 32 + ff]
                                                       : Wt1[k4 * 128 + j * 32 + (ff - 32)];
            }
        } else {
            if (t < 64) bhead[t] = (t < 32) ? bs1[t] : bt1[t - 32];
            if (t < 160) {
                const int c = t >> 5, jj = t & 31;
                wfin[t] = (c == 0) ? Ws2[jj] : Wt2[jj * 4 + (c - 1)];
            }
            if (t < 5) bfin[t] = (t == 0) ? bs2[0] : bt2[t - 1];
        }
    }
}

// ------- dispatch 2: bucket sort (R19/R21-verified) ----------------------------------
__global__ __launch_bounds__(1024) void bucket_sort_kernel(
    const unsigned* __restrict__ staging, const int* __restrict__ bfill,
    int* __restrict__ sdst, int* __restrict__ offs, int* __restrict__ counts)
{
    __shared__ int ldst[ECAP];           // 20 KB
    __shared__ int cntS[BNODES];
    __shared__ int scanS[BNODES];
    __shared__ int lstart[BNODES];
    __shared__ int lcur[BNODES];
    const int t = threadIdx.x;
    const int b = blockIdx.x;
    const int base0 = b * ECAP;
    const int ecnt  = bfill[b];

    if (t < BNODES) cntS[t] = 0;
    __syncthreads();

    const uint4 e0 = *reinterpret_cast<const uint4*>(&staging[base0 + t * 4]);
    uint4 e1 = make_uint4(0u, 0u, 0u, 0u);
    if (ecnt > 4096)                     // block-uniform branch
        e1 = *reinterpret_cast<const uint4*>(&staging[base0 + 4096 + t * 4]);
    const unsigned ev[8] = {e0.x, e0.y, e0.z, e0.w, e1.x, e1.y, e1.z, e1.w};
    int iv[8];
    #pragma unroll
    for (int u = 0; u < 8; ++u)
        iv[u] = (u < 4) ? (t * 4 + u) : (4096 + t * 4 + (u - 4));

    #pragma unroll
    for (int u = 0; u < 8; ++u)
        if (iv[u] < ecnt) atomicAdd(&cntS[ev[u] >> 17], 1);
    __syncthreads();

    if (t < BNODES) scanS[t] = (cntS[t] + 3) & ~3;   // padded counts
    __syncthreads();
    for (int off = 1; off < BNODES; off <<= 1) {
        int xv = 0;
        if (t >= off && t < BNODES) xv = scanS[t - off];
        __syncthreads();
        if (t >= off && t < BNODES) scanS[t] += xv;
        __syncthreads();
    }
    if (t < BNODES) {
        const int st = scanS[t] - ((cntS[t] + 3) & ~3);
        lstart[t] = st;
        lcur[t]   = st;
    }
    __syncthreads();

    #pragma unroll
    for (int u = 0; u < 8; ++u)
        if (iv[u] < ecnt) {
            const int lp = atomicAdd(&lcur[(int)(ev[u] >> 17)], 1);
            ldst[lp] = (int)(ev[u] & 0x1FFFFu);
        }
    __syncthreads();

    const int tot4 = scanS[BNODES - 1];              // padded total (< ECAP)
    for (int i = t * 4; i < tot4; i += 4096)
        *reinterpret_cast<int4*>(&sdst[base0 + i]) =
            *reinterpret_cast<const int4*>(&ldst[i]);   // gaps garbage (masked later)

    const int nbase = b * BNODES;
    if (t < BNODES && nbase + t < NN) {
        offs[nbase + t]   = base0 + lstart[t];
        counts[nbase + t] = cntS[t];
    }
}

// ------- dispatch 3: fused gather(mean)+MLP+heads — R16/R21-verified 104.7us form ----
// Floored: R19 (3-bank, compiler-serialized) and R22 (static schedule, spilled at
// VGPR 64 / WRITE_SIZE 8.6k) both lost to this 2-bank structure. Occupancy ~49% is
// the 1-wave WG-dispatch cap (1-wave beats 2/4-wave: R15/R16/R18 A/B).
#define ACC4(cv, u)                                                            \
    {                                                                          \
        const float m = (rem > (u)) ? 1.0f : 0.0f;                             \
        const __half2* ph = reinterpret_cast<const __half2*>(&(cv));           \
        const float2 p0 = __half22float2(ph[0]);                               \
        const float2 p1 = __half22float2(ph[1]);                               \
        const float2 p2 = __half22float2(ph[2]);                               \
        const float2 p3 = __half22float2(ph[3]);                               \
        acc0 = fmaf(m, p0.x, acc0); acc1 = fmaf(m, p0.y, acc1);                \
        acc2 = fmaf(m, p1.x, acc2); acc3 = fmaf(m, p1.y, acc3);                \
        acc4 = fmaf(m, p2.x, acc4); acc5 = fmaf(m, p2.y, acc5);                \
        acc6 = fmaf(m, p3.x, acc6); acc7 = fmaf(m, p3.y, acc7);                \
    }

#define FLUSHN(jj)                                                             \
    {                                                                          \
        float4* w0 = reinterpret_cast<float4*>(&sp[r][g << 3]);                \
        w0[0] = make_float4(acc0, acc1, acc2, acc3);                           \
        w0[1] = make_float4(acc4, acc5, acc6, acc7);                           \
        const float ssum = sp[0][f] + sp[1][f] + sp[2][f] + sp[3][f]           \
                         + sp[4][f] + sp[5][f] + sp[6][f] + sp[7][f];          \
        const int dgj = DGf(jj);                                               \
        sa[jj][f] = SVf(jj) + ssum * (1.0f / fmaxf((float)dgj, 1.0f));         \
        acc0 = acc1 = acc2 = acc3 = acc4 = acc5 = acc6 = acc7 = 0.0f;          \
    }

#define GSTEP(c0, c1, c2, c3, n0_, n1_, n2_, n3_)                              \
    {                                                                          \
        if (jn < 4) { /* fill bank N for chunk (jn,bn) */                      \
            const int rem = DGf(jn) - bn - 4 * r;                              \
            const int i0 = (rem > 0) ? idxN.x : 0;                             \
            const int i1 = (rem > 1) ? idxN.y : 0;                             \
            const int i2 = (rem > 2) ? idxN.z : 0;                             \
            const int i3 = (rem > 3) ? idxN.w : 0;                             \
            n0_ = *reinterpret_cast<const int4*>(hbase + ((size_t)i0 << 6));   \
            n1_ = *reinterpret_cast<const int4*>(hbase + ((size_t)i1 << 6));   \
            n2_ = *reinterpret_cast<const int4*>(hbase + ((size_t)i2 << 6));   \
            n3_ = *reinterpret_cast<const int4*>(hbase + ((size_t)i3 << 6));   \
        }                                                                      \
        int jm = jn, bm = bn; adv(jm, bm);                                     \
        idxN = IDXL(jm, bm);                                                   \
        { /* consume bank C for chunk (jc,bc) */                               \
            const int rem = DGf(jc) - bc - 4 * r;                              \
            ACC4(c0, 0); ACC4(c1, 1); ACC4(c2, 2); ACC4(c3, 3);                \
        }                                                                      \
        if (jn != jc) FLUSHN(jc);                                              \
        jc = jn; bc = bn; jn = jm; bn = bm;                                    \
    }

__global__ __launch_bounds__(64, 4) void gather_head_kernel(
    const __half* __restrict__ h16,
    const int* __restrict__ counts, const int* __restrict__ offs,
    const int* __restrict__ sdst,
    const float* __restrict__ wf1t, const float* __restrict__ bf1,
    const float* __restrict__ wf2t, const float* __restrict__ bf2,
    const float* __restrict__ wht,  const float* __restrict__ bhead,
    const float* __restrict__ wfin, const float* __restrict__ bfin,
    float* __restrict__ out_scores, float* __restrict__ out_types)
{
    __shared__ float sa[4][H];
    __shared__ float sb[4][H];
    __shared__ float sp[8][H];           // 2 KB row-slot partials
    const int f  = threadIdx.x;          // 0..63
    const int n0 = blockIdx.x * 4;       // grid 25000 -> n0+3 < NN always
    const int g  = f & 7;                // feature-group (16B at g*16 within a row)
    const int r  = f >> 3;               // row-slot (4 consecutive edges per slot)
    const __half* __restrict__ hbase = h16 + (g << 3);

    const int dg0 = counts[n0 + 0], dg1 = counts[n0 + 1],
              dg2 = counts[n0 + 2], dg3 = counts[n0 + 3];
    const int st0 = offs[n0 + 0], st1 = offs[n0 + 1],
              st2 = offs[n0 + 2], st3 = offs[n0 + 3];

    const float sv0 = __half2float(h16[((size_t)(n0 + 0) << 6) + f]);
    const float sv1 = __half2float(h16[((size_t)(n0 + 1) << 6) + f]);
    const float sv2 = __half2float(h16[((size_t)(n0 + 2) << 6) + f]);
    const float sv3 = __half2float(h16[((size_t)(n0 + 3) << 6) + f]);
    sa[0][f] = sv0; sa[1][f] = sv1; sa[2][f] = sv2; sa[3][f] = sv3;  // deg-0 default

    auto DGf = [&](int j) { return j == 0 ? dg0 : j == 1 ? dg1 : j == 2 ? dg2 : dg3; };
    auto STf = [&](int j) { return j == 0 ? st0 : j == 1 ? st1 : j == 2 ? st2 : st3; };
    auto SVf = [&](int j) { return j == 0 ? sv0 : j == 1 ? sv1 : j == 2 ? sv2 : sv3; };
    auto adv = [&](int& j, int& b) {
        if (j >= 4) return;
        b += 32;
        if (b >= DGf(j)) { b = 0; do { ++j; } while (j < 4 && DGf(j) == 0); }
    };
    auto IDXL = [&](int j, int b) -> int4 {   // 16B-aligned: starts padded to 4 ints
        if (j < 4) return *reinterpret_cast<const int4*>(&sdst[STf(j) + b + 4 * r]);
        return make_int4(0, 0, 0, 0);
    };

    float acc0 = 0.f, acc1 = 0.f, acc2 = 0.f, acc3 = 0.f,
          acc4 = 0.f, acc5 = 0.f, acc6 = 0.f, acc7 = 0.f;
    int4 A0 = make_int4(0,0,0,0), A1 = A0, A2 = A0, A3 = A0;
    int4 B0 = A0, B1 = A0, B2 = A0, B3 = A0;

    // --- pipeline prologue ---
    int jc = 0, bc = 0;
    while (jc < 4 && DGf(jc) == 0) ++jc;
    int jn = jc, bn = bc; adv(jn, bn);
    int4 idxC = IDXL(jc, bc);
    int4 idxN = IDXL(jn, bn);
    if (jc < 4) {                         // fill bank A for first chunk
        const int rem = DGf(jc) - bc - 4 * r;
        const int i0 = (rem > 0) ? idxC.x : 0;
        const int i1 = (rem > 1) ? idxC.y : 0;
        const int i2 = (rem > 2) ? idxC.z : 0;
        const int i3 = (rem > 3) ? idxC.w : 0;
        A0 = *reinterpret_cast<const int4*>(hbase + ((size_t)i0 << 6));
        A1 = *reinterpret_cast<const int4*>(hbase + ((size_t)i1 << 6));
        A2 = *reinterpret_cast<const int4*>(hbase + ((size_t)i2 << 6));
        A3 = *reinterpret_cast<const int4*>(hbase + ((size_t)i3 << 6));
    }

    while (jc < 4) {
        GSTEP(A0, A1, A2, A3, B0, B1, B2, B3);
        if (jc >= 4) break;
        GSTEP(B0, B1, B2, B3, A0, A1, A2, A3);
    }

    // ---- layer 1: sa -> sb (relu), one weight dwordx4 feeds 4 k x 4 nodes ----
    {
        const float bb = bf1[f];
        float o0 = bb, o1 = bb, o2 = bb, o3 = bb;
        #pragma unroll
        for (int k4 = 0; k4 < 16; ++k4) {
            const float4 w  = *reinterpret_cast<const float4*>(&wf1t[(k4 * 64 + f) * 4]);
            const float4 a0 = *reinterpret_cast<const float4*>(&sa[0][k4 * 4]);
            const float4 a1 = *reinterpret_cast<const float4*>(&sa[1][k4 * 4]);
            const float4 a2 = *reinterpret_cast<const float4*>(&sa[2][k4 * 4]);
            const float4 a3 = *reinterpret_cast<const float4*>(&sa[3][k4 * 4]);
            o0 = fmaf(a0.x, w.x, o0); o0 = fmaf(a0.y, w.y, o0); o0 = fmaf(a0.z, w.z, o0); o0 = fmaf(a0.w, w.w, o0);
            o1 = fmaf(a1.x, w.x, o1); o1 = fmaf(a1.y, w.y, o1); o1 = fmaf(a1.z, w.z, o1); o1 = fmaf(a1.w, w.w, o1);
            o2 = fmaf(a2.x, w.x, o2); o2 = fmaf(a2.y, w.y, o2); o2 = fmaf(a2.z, w.z, o2); o2 = fmaf(a2.w, w.w, o2);
            o3 = fmaf(a3.x, w.x, o3); o3 = fmaf(a3.y, w.y, o3); o3 = fmaf(a3.z, w.z, o3); o3 = fmaf(a3.w, w.w, o3);
        }
        sb[0][f] = fmaxf(o0, 0.0f);
        sb[1][f] = fmaxf(o1, 0.0f);
        sb[2][f] = fmaxf(o2, 0.0f);
        sb[3][f] = fmaxf(o3, 0.0f);
    }

    // ---- layer 2: sb -> sa (relu) ----
    {
        const float bb = bf2[f];
        float o0 = bb, o1 = bb, o2 = bb, o3 = bb;
        #pragma unroll
        for (int k4 = 0; k4 < 16; ++k4) {
            const float4 w  = *reinterpret_cast<const float4*>(&wf2t[(k4 * 64 + f) * 4]);
            const float4 a0 = *reinterpret_cast<const float4*>(&sb[0][k4 * 4]);
            const float4 a1 = *reinterpret_cast<const float4*>(&sb[1][k4 * 4]);
            const float4 a2 = *reinterpret_cast<const float4*>(&sb[2][k4 * 4]);
            const float4 a3 = *reinterpret_cast<const float4*>(&sb[3][k4 * 4]);
            o0 = fmaf(a0.x, w.x, o0); o0 = fmaf(a0.y, w.y, o0); o0 = fmaf(a0.z, w.z, o0); o0 = fmaf(a0.w, w.w, o0);
            o1 = fmaf(a1.x, w.x, o1); o1 = fmaf(a1.y, w.y, o1); o1 = fmaf(a1.z, w.z, o1); o1 = fmaf(a1.w, w.w, o1);
            o2 = fmaf(a2.x, w.x, o2); o2 = fmaf(a2.y, w.y, o2); o2 = fmaf(a2.z, w.z, o2); o2 = fmaf(a2.w, w.w, o2);
            o3 = fmaf(a3.x, w.x, o3); o3 = fmaf(a3.y, w.y, o3); o3 = fmaf(a3.z, w.z, o3); o3 = fmaf(a3.w, w.w, o3);
        }
        sa[0][f] = fmaxf(o0, 0.0f);
        sa[1][f] = fmaxf(o1, 0.0f);
        sa[2][f] = fmaxf(o2, 0.0f);
        sa[3][f] = fmaxf(o3, 0.0f);
    }

    // ---- heads layer (merged Ws1|Wt1): sa -> sb (relu) ----
    {
        const float bb = bhead[f];
        float o0 = bb, o1 = bb, o2 = bb, o3 = bb;
        #pragma unroll
        for (int k4 = 0; k4 < 16; ++k4) {
            const float4 w  = *reinterpret_cast<const float4*>(&wht[(k4 * 64 + f) * 4]);
            const float4 a0 = *reinterpret_cast<const float4*>(&sa[0][k4 * 4]);
            const float4 a1 = *reinterpret_cast<const float4*>(&sa[1][k4 * 4]);
            const float4 a2 = *reinterpret_cast<const float4*>(&sa[2][k4 * 4]);
            const float4 a3 = *reinterpret_cast<const float4*>(&sa[3][k4 * 4]);
            o0 = fmaf(a0.x, w.x, o0); o0 = fmaf(a0.y, w.y, o0); o0 = fmaf(a0.z, w.z, o0); o0 = fmaf(a0.w, w.w, o0);
            o1 = fmaf(a1.x, w.x, o1); o1 = fmaf(a1.y, w.y, o1); o1 = fmaf(a1.z, w.z, o1); o1 = fmaf(a1.w, w.w, o1);
            o2 = fmaf(a2.x, w.x, o2); o2 = fmaf(a2.y, w.y, o2); o2 = fmaf(a2.z, w.z, o2); o2 = fmaf(a2.w, w.w, o2);
            o3 = fmaf(a3.x, w.x, o3); o3 = fmaf(a3.y, w.y, o3); o3 = fmaf(a3.z, w.z, o3); o3 = fmaf(a3.w, w.w, o3);
        }
        sb[0][f] = fmaxf(o0, 0.0f);
        sb[1][f] = fmaxf(o1, 0.0f);
        sb[2][f] = fmaxf(o2, 0.0f);
        sb[3][f] = fmaxf(o3, 0.0f);
    }

    // ---- final: j = f>>4 (node), c = f&15 (output, active c<5); rotated start ----
    {
        const int j = f >> 4;
        const int c = f & 15;
        if (c < 5) {
            float a2 = bfin[c];
            const int off = (c == 0) ? 0 : 32;
            const int rot = ((c << 2) + (j << 3)) & 31;
            #pragma unroll 8
            for (int jj = 0; jj < 32; ++jj) {
                const int q = (jj + rot) & 31;
                a2 = fmaf(sb[j][off + q], wfin[c * 32 + q], a2);
            }
            const int node = n0 + j;
            if (c == 0) out_scores[node] = a2;
            else        out_types[node * 4 + (c - 1)] = a2;
        }
    }
}

#undef GSTEP
#undef FLUSHN
#undef ACC4

extern "C" void kernel_launch(void* const* d_in, const int* in_sizes, int n_in,
                              void* d_out, int out_size, void* d_ws, size_t ws_size,
                              hipStream_t stream)
{
    const float* x   = (const float*)d_in[0];
    const int*   adj = (const int*)  d_in[1];   // [2, E]: src = adj[0:E], dst = adj[E:2E]
    const float* W1  = (const float*)d_in[2];
    const float* b1  = (const float*)d_in[3];
    const float* W2  = (const float*)d_in[4];
    const float* b2  = (const float*)d_in[5];
    const float* Wf1 = (const float*)d_in[6];
    const float* bf1 = (const float*)d_in[7];
    const float* Wf2 = (const float*)d_in[8];
    const float* bf2 = (const float*)d_in[9];
    const float* Ws1 = (const float*)d_in[10];
    const float* bs1 = (const float*)d_in[11];
    const float* Ws2 = (const float*)d_in[12];
    const float* bs2 = (const float*)d_in[13];
    const float* Wt1 = (const float*)d_in[14];
    const float* bt1 = (const float*)d_in[15];
    const float* Wt2 = (const float*)d_in[16];
    const float* bt2 = (const float*)d_in[17];

    float* out_scores = (float*)d_out;          // [N]
    float* out_types  = out_scores + NN;        // [N,4]

    // ws: staging [NB*ECAP u32] | sdst [NB*ECAP] | h16 [NN*H half] | counts [NN]
    //     | offs [NN] | bfill [784] | wf1t[4096] wf2t[4096] wht[4096]
    //     | bhead[64] wfin[160] bfin[5]
    unsigned* staging = (unsigned*)d_ws;
    int*      sdst    = (int*)(staging + (size_t)NB * ECAP);
    __half*   h16     = (__half*)(sdst + (size_t)NB * ECAP);
    int*      counts  = (int*)(h16 + (size_t)NN * H);
    int*      offs    = counts + NN;
    int*      bfill   = offs + NN;
    float*    wf1t    = (float*)(bfill + 784);   // 16B-aligned (checked)
    float*    wf2t    = wf1t + 4096;
    float*    wht     = wf2t + 4096;
    float*    bhead   = wht + 4096;
    float*    wfin    = bhead + 64;
    float*    bfin    = wfin + 160;

    const int* src = adj;
    const int* dst = adj + NE;

    hipMemsetAsync(bfill, 0, NB * sizeof(int), stream);   // ws is poisoned
    fused_pre_kernel<<<NFUSED, PTHREADS, 0, stream>>>(
        src, dst, bfill, staging,
        x, W1, b1, W2, b2, h16,
        Wf1, Wf2, Ws1, bs1, Ws2, bs2, Wt1, bt1, Wt2, bt2,
        wf1t, wf2t, wht, bhead, wfin, bfin);
    bucket_sort_kernel<<<NB, 1024, 0, stream>>>(staging, bfill, sdst, offs, counts);
    gather_head_kernel<<<NN / 4, 64, 0, stream>>>(h16, counts, offs, sdst,
                                                  wf1t, bf1, wf2t, bf2,
                                                  wht, bhead, wfin, bfin,
                                                  out_scores, out_types);
}